// Round 6
// baseline (230.930 us; speedup 1.0000x reference)
//
#include <hip/hip_runtime.h>
#include <hip/hip_bf16.h>

// GCN: out = (segment_sum over edges+selfloops of norm * emb[src]) @ W, gathered at `nodes`.
// Strategy: filter edges to targets in `nodes` (~9.5% of 1.6M), aggregate 512-dim f32
// embeddings per unique target, then 512x128 dot -- fused, 16 targets per block.
// Round 5->6: multi-target blocks kill the per-row W re-stream (2.4 GB -> ~0.3 GB L2):
// round-5's 1-row-per-block fusion made every block read all 256 KB of W.
// Gather: wave owns 2 slots, lane covers cols (lane, lane+64); LDS = exactly 40 KB
// (accs 32K + sidx 4K + swgt 4K) -> 4 blocks/CU, 100% occupancy, 625 blocks all resident.

constexpr int KDIM = 512;   // embedding dim
constexpr int CDIM = 128;   // output channels
constexpr int CAPB = 64;    // bucket capacity per slot (Poisson(16); P(X>=64)~1e-19)
constexpr int CAPO = 16;    // max duplicate output rows per node
constexpr int TPB  = 16;    // targets per k_aggmm block

// ---- fused initialization: deg=0, tmap=-1, cur=0, ocnt=0, ucount=0 ----
__global__ void k_init(int* __restrict__ deg, int* __restrict__ tmap,
                       int* __restrict__ cur, int* __restrict__ ocnt,
                       int* __restrict__ ucount, int N, int n) {
    int i = blockIdx.x * blockDim.x + threadIdx.x;
    if (i < N) { deg[i] = 0; tmap[i] = -1; }
    if (i < n) { cur[i] = 0; ocnt[i] = 0; }
    if (i == 0) *ucount = 0;
}

// ---- unique-target compaction: tmap[node] = slot or -1 ----
__global__ void k_targets(const int* __restrict__ nodes, int n,
                          int* __restrict__ tmap, int* __restrict__ tlist,
                          int* __restrict__ ucount) {
    int i = blockIdx.x * blockDim.x + threadIdx.x;
    if (i >= n) return;
    int v = nodes[i];
    if (atomicCAS(&tmap[v], -1, -2) == -1) {   // claim
        int slot = atomicAdd(ucount, 1);
        tlist[slot] = v;
        tmap[v] = slot;                        // only the claimer writes
    }
}

// ---- slot -> list of output rows (handles duplicate nodes) ----
__global__ void k_outmap(const int* __restrict__ nodes, int n,
                         const int* __restrict__ tmap,
                         int* __restrict__ ocnt, int* __restrict__ olist) {
    int i = blockIdx.x * blockDim.x + threadIdx.x;
    if (i >= n) return;
    int slot = tmap[nodes[i]];                 // always >= 0 after k_targets
    int p = atomicAdd(&ocnt[slot], 1);
    if (p < CAPO) olist[slot * CAPO + p] = i;
}

// ---- single edge pass: deg atomics + capacity-bucket fill ----
__global__ __launch_bounds__(256)
void k_degfill(const int* __restrict__ erow, const int* __restrict__ ecol, int E,
               int* __restrict__ deg, const int* __restrict__ tmap,
               int* __restrict__ cur, int* __restrict__ ebuf) {
    int t = blockIdx.x * blockDim.x + threadIdx.x;
    int base = t * 4;
    if (base >= E) return;
    if (base + 4 <= E) {
        int4 c = *reinterpret_cast<const int4*>(ecol + base);
        atomicAdd(&deg[c.x], 1);
        atomicAdd(&deg[c.y], 1);
        atomicAdd(&deg[c.z], 1);
        atomicAdd(&deg[c.w], 1);
        int s0 = tmap[c.x], s1 = tmap[c.y], s2 = tmap[c.z], s3 = tmap[c.w];
        if ((s0 >= 0) | (s1 >= 0) | (s2 >= 0) | (s3 >= 0)) {
            int4 r = *reinterpret_cast<const int4*>(erow + base);
            if (s0 >= 0) { int p = atomicAdd(&cur[s0], 1); if (p < CAPB) ebuf[s0 * CAPB + p] = r.x; }
            if (s1 >= 0) { int p = atomicAdd(&cur[s1], 1); if (p < CAPB) ebuf[s1 * CAPB + p] = r.y; }
            if (s2 >= 0) { int p = atomicAdd(&cur[s2], 1); if (p < CAPB) ebuf[s2 * CAPB + p] = r.z; }
            if (s3 >= 0) { int p = atomicAdd(&cur[s3], 1); if (p < CAPB) ebuf[s3 * CAPB + p] = r.w; }
        }
    } else {
        for (int i = base; i < E; ++i) {
            int c = ecol[i];
            atomicAdd(&deg[c], 1);
            int s = tmap[c];
            if (s >= 0) { int p = atomicAdd(&cur[s], 1); if (p < CAPB) ebuf[s * CAPB + p] = erow[i]; }
        }
    }
}

// ---- fused per-16-targets: aggregate 512-dim rows + (16x512)@(512x128) + out ----
// 512 threads. Gather: wave w (of 8) owns slots 2w,2w+1; lane covers float4 cols
// lane and lane+64 (2x1KB coalesced per source row). GEMM: rg=tid>>5 row,
// c4=(tid&31)*4 cols; accs broadcast from LDS, W streamed (16-row reuse).
__global__ __launch_bounds__(512)
void k_aggmm(const float* __restrict__ emb, const float* __restrict__ W,
             const int* __restrict__ deg, const int* __restrict__ tlist,
             const int* __restrict__ cur, const int* __restrict__ ebuf,
             const int* __restrict__ ucount, const int* __restrict__ ocnt,
             const int* __restrict__ olist, float* __restrict__ out) {
    __shared__ float accs[TPB][KDIM];   // 32 KB
    __shared__ int   sidx[TPB][CAPB];   // 4 KB
    __shared__ float swgt[TPB][CAPB];   // 4 KB   -> total exactly 40 KB
    int u = *ucount;
    int slot0 = blockIdx.x * TPB;
    if (slot0 >= u) return;             // uniform whole-block exit
    int tid = threadIdx.x;

    // preload bucket indices + weights (coalesced ebuf, random deg gathers)
    for (int idx = tid; idx < TPB * CAPB; idx += 512) {
        int ls = idx / CAPB, j = idx % CAPB;
        int s = slot0 + ls;
        int e = (s < u) ? min(cur[s], CAPB) : 0;
        if (j < e) {
            int src = ebuf[(size_t)s * CAPB + j];
            sidx[ls][j] = src;
            swgt[ls][j] = rsqrtf((float)(deg[src] + 1));
        }
    }
    __syncthreads();

    // gather: wave owns 2 slots
    int wave = tid >> 6, lane = tid & 63;
    #pragma unroll
    for (int q = 0; q < 2; ++q) {
        int ls = (wave << 1) | q;
        int s = slot0 + ls;
        int e = (s < u) ? min(cur[s], CAPB) : 0;
        float4 a0 = {0.f, 0.f, 0.f, 0.f}, a1 = {0.f, 0.f, 0.f, 0.f};
        #pragma unroll 4
        for (int j = 0; j < e; ++j) {
            float w = swgt[ls][j];
            const float4* row = reinterpret_cast<const float4*>(emb + (size_t)sidx[ls][j] * KDIM);
            float4 v0 = row[lane];
            float4 v1 = row[lane + 64];
            a0.x += w * v0.x; a0.y += w * v0.y; a0.z += w * v0.z; a0.w += w * v0.w;
            a1.x += w * v1.x; a1.y += w * v1.y; a1.z += w * v1.z; a1.w += w * v1.w;
        }
        if (s < u) {
            int t = tlist[s];
            float dt = rsqrtf((float)(deg[t] + 1));
            const float4* row = reinterpret_cast<const float4*>(emb + (size_t)t * KDIM);
            float4 v0 = row[lane];
            float4 v1 = row[lane + 64];
            float4 r0, r1;
            r0.x = dt * (a0.x + dt * v0.x); r0.y = dt * (a0.y + dt * v0.y);
            r0.z = dt * (a0.z + dt * v0.z); r0.w = dt * (a0.w + dt * v0.w);
            r1.x = dt * (a1.x + dt * v1.x); r1.y = dt * (a1.y + dt * v1.y);
            r1.z = dt * (a1.z + dt * v1.z); r1.w = dt * (a1.w + dt * v1.w);
            reinterpret_cast<float4*>(&accs[ls][0])[lane]      = r0;
            reinterpret_cast<float4*>(&accs[ls][0])[lane + 64] = r1;
        }
    }
    __syncthreads();

    // GEMM: out_row(rg)[c4..c4+3] = sum_k accs[rg][k] * W[k][c4..c4+3]
    int rg = tid >> 5;                  // 16 rows
    int c4 = (tid & 31) * 4;            // 128 cols
    float4 o = {0.f, 0.f, 0.f, 0.f};
    #pragma unroll 8
    for (int k = 0; k < KDIM; ++k) {
        float4 w = *reinterpret_cast<const float4*>(W + (size_t)k * CDIM + c4);
        float a = accs[rg][k];          // LDS broadcast within half-wave
        o.x += a * w.x; o.y += a * w.y; o.z += a * w.z; o.w += a * w.w;
    }
    int s = slot0 + rg;
    if (s < u) {
        int cnt = min(ocnt[s], CAPO);
        for (int q = 0; q < cnt; ++q) {
            int i = olist[s * CAPO + q];
            *reinterpret_cast<float4*>(out + (size_t)i * CDIM + c4) = o;
        }
    }
}

extern "C" void kernel_launch(void* const* d_in, const int* in_sizes, int n_in,
                              void* d_out, int out_size, void* d_ws, size_t ws_size,
                              hipStream_t stream) {
    const int*   nodes = (const int*)d_in[0];
    const int*   eidx  = (const int*)d_in[1];
    const float* emb   = (const float*)d_in[2];
    const float* W     = (const float*)d_in[3];
    float*       out   = (float*)d_out;

    int n = in_sizes[0];             // 10000
    int E = in_sizes[1] / 2;         // 1,600,000
    int N = in_sizes[2] / KDIM;      // 100,000
    const int* erow = eidx;          // sources
    const int* ecol = eidx + E;      // targets

    // workspace carve (~4.5 MB total)
    char* ws = (char*)d_ws;
    size_t o = 0;
    auto carve = [&](size_t bytes) {
        char* p = ws + o;
        o = (o + bytes + 255) & ~(size_t)255;
        return p;
    };
    int* deg    = (int*)carve((size_t)N * 4);
    int* tmap   = (int*)carve((size_t)N * 4);
    int* tlist  = (int*)carve((size_t)n * 4);
    int* cur    = (int*)carve((size_t)n * 4);
    int* ocnt   = (int*)carve((size_t)n * 4);
    int* olist  = (int*)carve((size_t)n * CAPO * 4);
    int* ucount = (int*)carve(4);
    int* ebuf   = (int*)carve((size_t)n * CAPB * 4);
    (void)ws_size; (void)n_in; (void)out_size;

    int E4 = (E + 3) / 4;
    k_init   <<<(N + 255) / 256, 256, 0, stream>>>(deg, tmap, cur, ocnt, ucount, N, n);
    k_targets<<<(n + 255) / 256, 256, 0, stream>>>(nodes, n, tmap, tlist, ucount);
    k_outmap <<<(n + 255) / 256, 256, 0, stream>>>(nodes, n, tmap, ocnt, olist);
    k_degfill<<<(E4 + 255) / 256, 256, 0, stream>>>(erow, ecol, E, deg, tmap, cur, ebuf);
    k_aggmm  <<<(n + TPB - 1) / TPB, 512, 0, stream>>>(emb, W, deg, tlist, cur, ebuf,
                                                       ucount, ocnt, olist, out);
}

// Round 7
// 190.498 us; speedup vs baseline: 1.2122x; 1.2122x over previous
//
#include <hip/hip_runtime.h>
#include <hip/hip_bf16.h>

// GCN: out = (segment_sum over edges+selfloops of norm * emb[src]) @ W, gathered at `nodes`.
// Round 7 restructure: commute GEMM before gather.
//   h = emb @ W  (dense bf16 MFMA, all 100k nodes, HBM-streamed)   ~45-60 us
//   aggregate h rows (512 B bf16, 4x less gather bytes, L2-resident) per target
// Rounds 4-6 showed gather+per-target GEMM is latency/L2-bound at ~160 us regardless
// of schedule (replay FETCH=5MB, same duration) -> shrink bytes per edge instead.

constexpr int KDIM = 512;   // embedding dim
constexpr int CDIM = 128;   // output channels
constexpr int CAPB = 64;    // bucket capacity per slot (Poisson(16); P(X>=64)~1e-19)
constexpr int CAPO = 16;    // max duplicate output rows per node

typedef __attribute__((ext_vector_type(8))) short short8;   // 8 bf16 (A/B frag)
typedef __attribute__((ext_vector_type(4))) float f32x4;    // C/D frag

static __device__ __forceinline__ unsigned short f2bf(float f) {
    unsigned u = __float_as_uint(f);
    unsigned r = ((u >> 16) & 1u) + 0x7fffu;     // round-to-nearest-even
    return (unsigned short)((u + r) >> 16);
}
static __device__ __forceinline__ float bf2f(unsigned short b) {
    return __uint_as_float(((unsigned)b) << 16);
}

// ---- fused initialization: deg=0, tmap=-1, cur=0, ocnt=0, ucount=0 ----
__global__ void k_init(int* __restrict__ deg, int* __restrict__ tmap,
                       int* __restrict__ cur, int* __restrict__ ocnt,
                       int* __restrict__ ucount, int N, int n) {
    int i = blockIdx.x * blockDim.x + threadIdx.x;
    if (i < N) { deg[i] = 0; tmap[i] = -1; }
    if (i < n) { cur[i] = 0; ocnt[i] = 0; }
    if (i == 0) *ucount = 0;
}

// ---- unique-target compaction: tmap[node] = slot or -1 ----
__global__ void k_targets(const int* __restrict__ nodes, int n,
                          int* __restrict__ tmap, int* __restrict__ tlist,
                          int* __restrict__ ucount) {
    int i = blockIdx.x * blockDim.x + threadIdx.x;
    if (i >= n) return;
    int v = nodes[i];
    if (atomicCAS(&tmap[v], -1, -2) == -1) {   // claim
        int slot = atomicAdd(ucount, 1);
        tlist[slot] = v;
        tmap[v] = slot;                        // only the claimer writes
    }
}

// ---- slot -> list of output rows (handles duplicate nodes) ----
__global__ void k_outmap(const int* __restrict__ nodes, int n,
                         const int* __restrict__ tmap,
                         int* __restrict__ ocnt, int* __restrict__ olist) {
    int i = blockIdx.x * blockDim.x + threadIdx.x;
    if (i >= n) return;
    int slot = tmap[nodes[i]];                 // always >= 0 after k_targets
    int p = atomicAdd(&ocnt[slot], 1);
    if (p < CAPO) olist[slot * CAPO + p] = i;
}

// ---- single edge pass: deg atomics + capacity-bucket fill ----
__global__ __launch_bounds__(256)
void k_degfill(const int* __restrict__ erow, const int* __restrict__ ecol, int E,
               int* __restrict__ deg, const int* __restrict__ tmap,
               int* __restrict__ cur, int* __restrict__ ebuf) {
    int t = blockIdx.x * blockDim.x + threadIdx.x;
    int base = t * 4;
    if (base >= E) return;
    if (base + 4 <= E) {
        int4 c = *reinterpret_cast<const int4*>(ecol + base);
        atomicAdd(&deg[c.x], 1);
        atomicAdd(&deg[c.y], 1);
        atomicAdd(&deg[c.z], 1);
        atomicAdd(&deg[c.w], 1);
        int s0 = tmap[c.x], s1 = tmap[c.y], s2 = tmap[c.z], s3 = tmap[c.w];
        if ((s0 >= 0) | (s1 >= 0) | (s2 >= 0) | (s3 >= 0)) {
            int4 r = *reinterpret_cast<const int4*>(erow + base);
            if (s0 >= 0) { int p = atomicAdd(&cur[s0], 1); if (p < CAPB) ebuf[s0 * CAPB + p] = r.x; }
            if (s1 >= 0) { int p = atomicAdd(&cur[s1], 1); if (p < CAPB) ebuf[s1 * CAPB + p] = r.y; }
            if (s2 >= 0) { int p = atomicAdd(&cur[s2], 1); if (p < CAPB) ebuf[s2 * CAPB + p] = r.z; }
            if (s3 >= 0) { int p = atomicAdd(&cur[s3], 1); if (p < CAPB) ebuf[s3 * CAPB + p] = r.w; }
        }
    } else {
        for (int i = base; i < E; ++i) {
            int c = ecol[i];
            atomicAdd(&deg[c], 1);
            int s = tmap[c];
            if (s >= 0) { int p = atomicAdd(&cur[s], 1); if (p < CAPB) ebuf[s * CAPB + p] = erow[i]; }
        }
    }
}

// ---- pack W (512x128 f32) into bf16 MFMA B-fragment layout ----
// frag (s,t): lane l holds B[k][c] for k = s*32 + (l>>4)*8 + j (j=0..7),
// c = t*16 + (l&15).  Linear: wt[((s*8+t)*64 + l)*8 + j].
__global__ void k_wprep(const float* __restrict__ W, unsigned short* __restrict__ wt) {
    int idx = blockIdx.x * 256 + threadIdx.x;   // 0..65535
    int j  = idx & 7;
    int l  = (idx >> 3) & 63;
    int st = idx >> 9;
    int t  = st & 7, s = st >> 3;
    int k  = s * 32 + (l >> 4) * 8 + j;
    int c  = t * 16 + (l & 15);
    wt[idx] = f2bf(W[(size_t)k * CDIM + c]);
}

// ---- dense h = emb @ W, bf16 MFMA 16x16x32, h stored bf16 ----
// 256 thr = 4 waves; wave handles 16 rows x 128 cols; K=512 in 16 steps.
__global__ __launch_bounds__(256)
void k_gemm_h(const float* __restrict__ emb, const unsigned short* __restrict__ wt,
              unsigned short* __restrict__ h, int N) {
    int tid  = threadIdx.x;
    int wave = tid >> 6, lane = tid & 63;
    int rowA = blockIdx.x * 64 + wave * 16 + (lane & 15);   // A-frag row
    int kb   = lane >> 4;                                    // k-block 0..3
    bool valid = rowA < N;
    const float* abase = emb + (size_t)rowA * KDIM + kb * 8;
    const short8* wbase = reinterpret_cast<const short8*>(wt);

    f32x4 acc[8];
    #pragma unroll
    for (int t = 0; t < 8; ++t) acc[t] = (f32x4){0.f, 0.f, 0.f, 0.f};

    for (int s = 0; s < 16; ++s) {
        short8 af;
        if (valid) {
            float4 x = *reinterpret_cast<const float4*>(abase + s * 32);
            float4 y = *reinterpret_cast<const float4*>(abase + s * 32 + 4);
            af[0] = (short)f2bf(x.x); af[1] = (short)f2bf(x.y);
            af[2] = (short)f2bf(x.z); af[3] = (short)f2bf(x.w);
            af[4] = (short)f2bf(y.x); af[5] = (short)f2bf(y.y);
            af[6] = (short)f2bf(y.z); af[7] = (short)f2bf(y.w);
        } else {
            af = (short8){0, 0, 0, 0, 0, 0, 0, 0};
        }
        const short8* wp = wbase + (size_t)(s * 8) * 64 + lane;
        #pragma unroll
        for (int t = 0; t < 8; ++t) {
            short8 bf = wp[t * 64];
            acc[t] = __builtin_amdgcn_mfma_f32_16x16x32_bf16(af, bf, acc[t], 0, 0, 0);
        }
    }
    // D layout (m89-verified): col = lane&15, row = (lane>>4)*4 + reg_idx
    int rbase = blockIdx.x * 64 + wave * 16 + (lane >> 4) * 4;
    int col   = lane & 15;
    #pragma unroll
    for (int t = 0; t < 8; ++t) {
        #pragma unroll
        for (int j = 0; j < 4; ++j) {
            int r = rbase + j;
            if (r < N) h[(size_t)r * CDIM + t * 16 + col] = f2bf(acc[t][j]);
        }
    }
}

// ---- per-target aggregation over h (128-dim bf16): one wave per slot ----
__global__ __launch_bounds__(256)
void k_agg(const unsigned short* __restrict__ h, const int* __restrict__ deg,
           const int* __restrict__ tlist, const int* __restrict__ cur,
           const int* __restrict__ ebuf, const int* __restrict__ ucount,
           const int* __restrict__ ocnt, const int* __restrict__ olist,
           float* __restrict__ out) {
    int u = *ucount;
    int slot = blockIdx.x * 4 + (threadIdx.x >> 6);
    if (slot >= u) return;                 // wave-uniform exit
    int lane = threadIdx.x & 63;
    int e = min(cur[slot], CAPB);
    int myi = 0; float myw = 0.f;
    if (lane < e) {
        myi = ebuf[(size_t)slot * CAPB + lane];          // coalesced
        myw = rsqrtf((float)(deg[myi] + 1));
    }
    float ax = 0.f, ay = 0.f;
    #pragma unroll 4
    for (int j = 0; j < e; ++j) {
        int   src = __shfl(myi, j, 64);
        float w   = __shfl(myw, j, 64);
        unsigned v = *reinterpret_cast<const unsigned*>(h + (size_t)src * CDIM + lane * 2);
        ax += w * bf2f((unsigned short)(v & 0xffffu));
        ay += w * bf2f((unsigned short)(v >> 16));
    }
    int t = tlist[slot];
    float dt = rsqrtf((float)(deg[t] + 1));
    unsigned v = *reinterpret_cast<const unsigned*>(h + (size_t)t * CDIM + lane * 2);
    float rx = dt * (ax + dt * bf2f((unsigned short)(v & 0xffffu)));
    float ry = dt * (ay + dt * bf2f((unsigned short)(v >> 16)));
    int cnt = min(ocnt[slot], CAPO);
    for (int q = 0; q < cnt; ++q) {
        int i = olist[slot * CAPO + q];
        float2 o; o.x = rx; o.y = ry;
        *reinterpret_cast<float2*>(out + (size_t)i * CDIM + lane * 2) = o;  // coalesced
    }
}

extern "C" void kernel_launch(void* const* d_in, const int* in_sizes, int n_in,
                              void* d_out, int out_size, void* d_ws, size_t ws_size,
                              hipStream_t stream) {
    const int*   nodes = (const int*)d_in[0];
    const int*   eidx  = (const int*)d_in[1];
    const float* emb   = (const float*)d_in[2];
    const float* W     = (const float*)d_in[3];
    float*       out   = (float*)d_out;

    int n = in_sizes[0];             // 10000
    int E = in_sizes[1] / 2;         // 1,600,000
    int N = in_sizes[2] / KDIM;      // 100,000
    const int* erow = eidx;          // sources
    const int* ecol = eidx + E;      // targets

    // workspace carve (~30 MB total)
    char* ws = (char*)d_ws;
    size_t o = 0;
    auto carve = [&](size_t bytes) {
        char* p = ws + o;
        o = (o + bytes + 255) & ~(size_t)255;
        return p;
    };
    int* deg    = (int*)carve((size_t)N * 4);
    int* tmap   = (int*)carve((size_t)N * 4);
    int* tlist  = (int*)carve((size_t)n * 4);
    int* cur    = (int*)carve((size_t)n * 4);
    int* ocnt   = (int*)carve((size_t)n * 4);
    int* olist  = (int*)carve((size_t)n * CAPO * 4);
    int* ucount = (int*)carve(4);
    int* ebuf   = (int*)carve((size_t)n * CAPB * 4);
    unsigned short* wt = (unsigned short*)carve((size_t)16 * 8 * 64 * 8 * 2);   // 128 KB
    unsigned short* h  = (unsigned short*)carve((size_t)N * CDIM * 2);          // 25.6 MB
    (void)ws_size; (void)n_in; (void)out_size;

    int E4 = (E + 3) / 4;
    k_init   <<<(N + 255) / 256, 256, 0, stream>>>(deg, tmap, cur, ocnt, ucount, N, n);
    k_targets<<<(n + 255) / 256, 256, 0, stream>>>(nodes, n, tmap, tlist, ucount);
    k_outmap <<<(n + 255) / 256, 256, 0, stream>>>(nodes, n, tmap, ocnt, olist);
    k_degfill<<<(E4 + 255) / 256, 256, 0, stream>>>(erow, ecol, E, deg, tmap, cur, ebuf);
    k_wprep  <<<256, 256, 0, stream>>>(W, wt);
    k_gemm_h <<<(N + 63) / 64, 256, 0, stream>>>(emb, wt, h, N);
    k_agg    <<<(n + 3) / 4, 256, 0, stream>>>(h, deg, tlist, cur, ebuf, ucount,
                                               ocnt, olist, out);
}

// Round 8
// 168.704 us; speedup vs baseline: 1.3688x; 1.1292x over previous
//
#include <hip/hip_runtime.h>
#include <hip/hip_bf16.h>

// GCN: out = (segment_sum over edges+selfloops of norm * emb[src]) @ W, gathered at `nodes`.
// Round 8: k_gemm_h rebuilt as staged MFMA GEMM (global_load_lds width-16, double-buffered
// A+W LDS tiles, XOR-swizzled A via pre-swizzled global source). Round 7's direct-from-
// global version was latency-bound (1 TB/s, 2 outstanding loads/wave); DMA staging keeps
// a full 32KB tile in flight per block.

constexpr int KDIM = 512;   // embedding dim
constexpr int CDIM = 128;   // output channels
constexpr int CAPB = 64;    // bucket capacity per slot (Poisson(16); P(X>=64)~1e-19)
constexpr int CAPO = 16;    // max duplicate output rows per node

typedef __attribute__((ext_vector_type(8))) short short8;   // 8 bf16 (A/B frag)
typedef __attribute__((ext_vector_type(4))) float f32x4;    // C/D frag

static __device__ __forceinline__ unsigned short f2bf(float f) {
    unsigned u = __float_as_uint(f);
    unsigned r = ((u >> 16) & 1u) + 0x7fffu;     // round-to-nearest-even
    return (unsigned short)((u + r) >> 16);
}
static __device__ __forceinline__ float bf2f(unsigned short b) {
    return __uint_as_float(((unsigned)b) << 16);
}

// ---- fused initialization: deg=0, tmap=-1, cur=0, ocnt=0, ucount=0 ----
__global__ void k_init(int* __restrict__ deg, int* __restrict__ tmap,
                       int* __restrict__ cur, int* __restrict__ ocnt,
                       int* __restrict__ ucount, int N, int n) {
    int i = blockIdx.x * blockDim.x + threadIdx.x;
    if (i < N) { deg[i] = 0; tmap[i] = -1; }
    if (i < n) { cur[i] = 0; ocnt[i] = 0; }
    if (i == 0) *ucount = 0;
}

// ---- unique-target compaction: tmap[node] = slot or -1 ----
__global__ void k_targets(const int* __restrict__ nodes, int n,
                          int* __restrict__ tmap, int* __restrict__ tlist,
                          int* __restrict__ ucount) {
    int i = blockIdx.x * blockDim.x + threadIdx.x;
    if (i >= n) return;
    int v = nodes[i];
    if (atomicCAS(&tmap[v], -1, -2) == -1) {   // claim
        int slot = atomicAdd(ucount, 1);
        tlist[slot] = v;
        tmap[v] = slot;                        // only the claimer writes
    }
}

// ---- slot -> list of output rows (handles duplicate nodes) ----
__global__ void k_outmap(const int* __restrict__ nodes, int n,
                         const int* __restrict__ tmap,
                         int* __restrict__ ocnt, int* __restrict__ olist) {
    int i = blockIdx.x * blockDim.x + threadIdx.x;
    if (i >= n) return;
    int slot = tmap[nodes[i]];                 // always >= 0 after k_targets
    int p = atomicAdd(&ocnt[slot], 1);
    if (p < CAPO) olist[slot * CAPO + p] = i;
}

// ---- single edge pass: deg atomics + capacity-bucket fill ----
__global__ __launch_bounds__(256)
void k_degfill(const int* __restrict__ erow, const int* __restrict__ ecol, int E,
               int* __restrict__ deg, const int* __restrict__ tmap,
               int* __restrict__ cur, int* __restrict__ ebuf) {
    int t = blockIdx.x * blockDim.x + threadIdx.x;
    int base = t * 4;
    if (base >= E) return;
    if (base + 4 <= E) {
        int4 c = *reinterpret_cast<const int4*>(ecol + base);
        atomicAdd(&deg[c.x], 1);
        atomicAdd(&deg[c.y], 1);
        atomicAdd(&deg[c.z], 1);
        atomicAdd(&deg[c.w], 1);
        int s0 = tmap[c.x], s1 = tmap[c.y], s2 = tmap[c.z], s3 = tmap[c.w];
        if ((s0 >= 0) | (s1 >= 0) | (s2 >= 0) | (s3 >= 0)) {
            int4 r = *reinterpret_cast<const int4*>(erow + base);
            if (s0 >= 0) { int p = atomicAdd(&cur[s0], 1); if (p < CAPB) ebuf[s0 * CAPB + p] = r.x; }
            if (s1 >= 0) { int p = atomicAdd(&cur[s1], 1); if (p < CAPB) ebuf[s1 * CAPB + p] = r.y; }
            if (s2 >= 0) { int p = atomicAdd(&cur[s2], 1); if (p < CAPB) ebuf[s2 * CAPB + p] = r.z; }
            if (s3 >= 0) { int p = atomicAdd(&cur[s3], 1); if (p < CAPB) ebuf[s3 * CAPB + p] = r.w; }
        }
    } else {
        for (int i = base; i < E; ++i) {
            int c = ecol[i];
            atomicAdd(&deg[c], 1);
            int s = tmap[c];
            if (s >= 0) { int p = atomicAdd(&cur[s], 1); if (p < CAPB) ebuf[s * CAPB + p] = erow[i]; }
        }
    }
}

// ---- pack W (512x128 f32) into bf16 MFMA B-fragment layout ----
// frag (s,t): lane l holds B[k][c] for k = s*32 + (l>>4)*8 + j (j=0..7),
// c = t*16 + (l&15).  Linear: wt[((s*8+t)*64 + l)*8 + j].
__global__ void k_wprep(const float* __restrict__ W, unsigned short* __restrict__ wt) {
    int idx = blockIdx.x * 256 + threadIdx.x;   // 0..65535
    int j  = idx & 7;
    int l  = (idx >> 3) & 63;
    int st = idx >> 9;
    int t  = st & 7, s = st >> 3;
    int k  = s * 32 + (l >> 4) * 8 + j;
    int c  = t * 16 + (l & 15);
    wt[idx] = f2bf(W[(size_t)k * CDIM + c]);
}

// ---- dense h = emb @ W, staged MFMA GEMM ----
// 256 thr / 4 waves, 64 rows x 128 cols per block, K-chunks of 64.
// A (f32) and W-frags (bf16) double-buffered in LDS via global_load_lds width 16.
// A source pre-swizzled: global 16B-chunk (chunk^(row&7)) lands at linear LDS chunk,
// so ds_read applies the same XOR -> bank-conflict-free (T2/m173 pattern).
__global__ __launch_bounds__(256)
void k_gemm_h(const float* __restrict__ emb, const unsigned short* __restrict__ wt,
              unsigned short* __restrict__ h, int N) {
    __shared__ float          sA[2][64 * 64];          // 2 x 16 KB
    __shared__ unsigned short sB[2][2 * 8 * 64 * 8];   // 2 x 16 KB
    int tid  = threadIdx.x;
    int wave = tid >> 6, lane = tid & 63;
    int row0 = blockIdx.x * 64;

    auto stage = [&](int buf, int kc) {
        // A: 4 passes x (16 rows x 16 chunks of 16B); source chunk XOR-swizzled
        #pragma unroll
        for (int p = 0; p < 4; ++p) {
            int row   = p * 16 + (tid >> 4);
            int chunk = tid & 15;
            int swz   = chunk ^ (row & 7);
            int rg    = row0 + row; if (rg >= N) rg = N - 1;
            const float* g = emb + (size_t)rg * KDIM + kc * 64 + swz * 4;
            float* l = &sA[buf][row * 64 + chunk * 4];
            __builtin_amdgcn_global_load_lds(
                (const __attribute__((address_space(1))) void*)g,
                (__attribute__((address_space(3))) void*)l, 16, 0, 0);
        }
        // W-frags for this K-chunk: 16 KB linear copy (already frag-ordered)
        #pragma unroll
        for (int p = 0; p < 4; ++p) {
            const unsigned short* g = wt + (size_t)kc * 8192 + (p * 256 + tid) * 8;
            unsigned short* l = &sB[buf][(p * 256 + tid) * 8];
            __builtin_amdgcn_global_load_lds(
                (const __attribute__((address_space(1))) void*)g,
                (__attribute__((address_space(3))) void*)l, 16, 0, 0);
        }
    };

    f32x4 acc[8];
    #pragma unroll
    for (int t = 0; t < 8; ++t) acc[t] = (f32x4){0.f, 0.f, 0.f, 0.f};

    int rl = wave * 16 + (lane & 15);   // local A row
    int g4 = lane >> 4;                 // k-subgroup 0..3

    stage(0, 0);
    __syncthreads();                    // vmcnt(0) drain + barrier
    for (int kc = 0; kc < 8; ++kc) {
        if (kc < 7) stage((kc + 1) & 1, kc + 1);   // fire-and-forget next tile
        int buf = kc & 1;
        #pragma unroll
        for (int kb = 0; kb < 2; ++kb) {
            int c0 = kb * 8 + g4 * 2;              // global 16B-chunk of k-range
            int p0 = c0 ^ (rl & 7);                // swizzled LDS chunk
            int p1 = p0 ^ 1;
            float4 v0 = *reinterpret_cast<const float4*>(&sA[buf][rl * 64 + p0 * 4]);
            float4 v1 = *reinterpret_cast<const float4*>(&sA[buf][rl * 64 + p1 * 4]);
            short8 af;
            af[0] = (short)f2bf(v0.x); af[1] = (short)f2bf(v0.y);
            af[2] = (short)f2bf(v0.z); af[3] = (short)f2bf(v0.w);
            af[4] = (short)f2bf(v1.x); af[5] = (short)f2bf(v1.y);
            af[6] = (short)f2bf(v1.z); af[7] = (short)f2bf(v1.w);
            const short8* wp = reinterpret_cast<const short8*>(
                &sB[buf][((size_t)(kb * 8) * 64 + lane) * 8]);
            #pragma unroll
            for (int t = 0; t < 8; ++t) {
                short8 bf = wp[t * 64];
                acc[t] = __builtin_amdgcn_mfma_f32_16x16x32_bf16(af, bf, acc[t], 0, 0, 0);
            }
        }
        __syncthreads();                // drains next-tile DMA + protects buffers
    }

    // D layout (m89-verified): col = lane&15, row = (lane>>4)*4 + reg_idx
    int rbase = row0 + wave * 16 + (lane >> 4) * 4;
    int col   = lane & 15;
    #pragma unroll
    for (int t = 0; t < 8; ++t) {
        #pragma unroll
        for (int j = 0; j < 4; ++j) {
            int r = rbase + j;
            if (r < N) h[(size_t)r * CDIM + t * 16 + col] = f2bf(acc[t][j]);
        }
    }
}

// ---- per-target aggregation over h (128-dim bf16): one wave per slot ----
__global__ __launch_bounds__(256)
void k_agg(const unsigned short* __restrict__ h, const int* __restrict__ deg,
           const int* __restrict__ tlist, const int* __restrict__ cur,
           const int* __restrict__ ebuf, const int* __restrict__ ucount,
           const int* __restrict__ ocnt, const int* __restrict__ olist,
           float* __restrict__ out) {
    int u = *ucount;
    int slot = blockIdx.x * 4 + (threadIdx.x >> 6);
    if (slot >= u) return;                 // wave-uniform exit
    int lane = threadIdx.x & 63;
    int e = min(cur[slot], CAPB);
    int myi = 0; float myw = 0.f;
    if (lane < e) {
        myi = ebuf[(size_t)slot * CAPB + lane];          // coalesced
        myw = rsqrtf((float)(deg[myi] + 1));
    }
    float ax = 0.f, ay = 0.f;
    #pragma unroll 4
    for (int j = 0; j < e; ++j) {
        int   src = __shfl(myi, j, 64);
        float w   = __shfl(myw, j, 64);
        unsigned v = *reinterpret_cast<const unsigned*>(h + (size_t)src * CDIM + lane * 2);
        ax += w * bf2f((unsigned short)(v & 0xffffu));
        ay += w * bf2f((unsigned short)(v >> 16));
    }
    int t = tlist[slot];
    float dt = rsqrtf((float)(deg[t] + 1));
    unsigned v = *reinterpret_cast<const unsigned*>(h + (size_t)t * CDIM + lane * 2);
    float rx = dt * (ax + dt * bf2f((unsigned short)(v & 0xffffu)));
    float ry = dt * (ay + dt * bf2f((unsigned short)(v >> 16)));
    int cnt = min(ocnt[slot], CAPO);
    for (int q = 0; q < cnt; ++q) {
        int i = olist[slot * CAPO + q];
        float2 o; o.x = rx; o.y = ry;
        *reinterpret_cast<float2*>(out + (size_t)i * CDIM + lane * 2) = o;  // coalesced
    }
}

extern "C" void kernel_launch(void* const* d_in, const int* in_sizes, int n_in,
                              void* d_out, int out_size, void* d_ws, size_t ws_size,
                              hipStream_t stream) {
    const int*   nodes = (const int*)d_in[0];
    const int*   eidx  = (const int*)d_in[1];
    const float* emb   = (const float*)d_in[2];
    const float* W     = (const float*)d_in[3];
    float*       out   = (float*)d_out;

    int n = in_sizes[0];             // 10000
    int E = in_sizes[1] / 2;         // 1,600,000
    int N = in_sizes[2] / KDIM;      // 100,000
    const int* erow = eidx;          // sources
    const int* ecol = eidx + E;      // targets

    // workspace carve (~30 MB total)
    char* ws = (char*)d_ws;
    size_t o = 0;
    auto carve = [&](size_t bytes) {
        char* p = ws + o;
        o = (o + bytes + 255) & ~(size_t)255;
        return p;
    };
    int* deg    = (int*)carve((size_t)N * 4);
    int* tmap   = (int*)carve((size_t)N * 4);
    int* tlist  = (int*)carve((size_t)n * 4);
    int* cur    = (int*)carve((size_t)n * 4);
    int* ocnt   = (int*)carve((size_t)n * 4);
    int* olist  = (int*)carve((size_t)n * CAPO * 4);
    int* ucount = (int*)carve(4);
    int* ebuf   = (int*)carve((size_t)n * CAPB * 4);
    unsigned short* wt = (unsigned short*)carve((size_t)16 * 8 * 64 * 8 * 2);   // 128 KB
    unsigned short* h  = (unsigned short*)carve((size_t)N * CDIM * 2);          // 25.6 MB
    (void)ws_size; (void)n_in; (void)out_size;

    int E4 = (E + 3) / 4;
    k_init   <<<(N + 255) / 256, 256, 0, stream>>>(deg, tmap, cur, ocnt, ucount, N, n);
    k_targets<<<(n + 255) / 256, 256, 0, stream>>>(nodes, n, tmap, tlist, ucount);
    k_outmap <<<(n + 255) / 256, 256, 0, stream>>>(nodes, n, tmap, ocnt, olist);
    k_degfill<<<(E4 + 255) / 256, 256, 0, stream>>>(erow, ecol, E, deg, tmap, cur, ebuf);
    k_wprep  <<<256, 256, 0, stream>>>(W, wt);
    k_gemm_h <<<(N + 63) / 64, 256, 0, stream>>>(emb, wt, h, N);
    k_agg    <<<(n + 3) / 4, 256, 0, stream>>>(h, deg, tlist, cur, ebuf, ucount,
                                               ocnt, olist, out);
}

// Round 9
// 158.563 us; speedup vs baseline: 1.4564x; 1.0640x over previous
//
#include <hip/hip_runtime.h>
#include <hip/hip_bf16.h>

// GCN: out = (segment_sum over edges+selfloops of norm * emb[src]) @ W, gathered at `nodes`.
// Round 9: k_gemm_h rebuilt with counted-vmcnt depth-2 pipeline (T3/T4):
// 3 LDS buffers (72 KB dynamic), BK=32, stage(kc+2) each iter, s_waitcnt vmcnt(6)
// + raw s_barrier (never drains to 0 in main loop). Round 8's __syncthreads drained
// the just-issued DMA every K-step -> ~94 us for a 37 us HBM-floor kernel.

constexpr int KDIM = 512;   // embedding dim
constexpr int CDIM = 128;   // output channels
constexpr int CAPB = 64;    // bucket capacity per slot (Poisson(16); P(X>=64)~1e-19)
constexpr int CAPO = 16;    // max duplicate output rows per node

typedef __attribute__((ext_vector_type(8))) short short8;   // 8 bf16 (A/B frag)
typedef __attribute__((ext_vector_type(4))) float f32x4;    // C/D frag

static __device__ __forceinline__ unsigned short f2bf(float f) {
    unsigned u = __float_as_uint(f);
    unsigned r = ((u >> 16) & 1u) + 0x7fffu;     // round-to-nearest-even
    return (unsigned short)((u + r) >> 16);
}
static __device__ __forceinline__ float bf2f(unsigned short b) {
    return __uint_as_float(((unsigned)b) << 16);
}

// ---- fused initialization: deg=0, tmap=-1, cur=0, ocnt=0, ucount=0 ----
__global__ void k_init(int* __restrict__ deg, int* __restrict__ tmap,
                       int* __restrict__ cur, int* __restrict__ ocnt,
                       int* __restrict__ ucount, int N, int n) {
    int i = blockIdx.x * blockDim.x + threadIdx.x;
    if (i < N) { deg[i] = 0; tmap[i] = -1; }
    if (i < n) { cur[i] = 0; ocnt[i] = 0; }
    if (i == 0) *ucount = 0;
}

// ---- unique-target compaction: tmap[node] = slot or -1 ----
__global__ void k_targets(const int* __restrict__ nodes, int n,
                          int* __restrict__ tmap, int* __restrict__ tlist,
                          int* __restrict__ ucount) {
    int i = blockIdx.x * blockDim.x + threadIdx.x;
    if (i >= n) return;
    int v = nodes[i];
    if (atomicCAS(&tmap[v], -1, -2) == -1) {   // claim
        int slot = atomicAdd(ucount, 1);
        tlist[slot] = v;
        tmap[v] = slot;                        // only the claimer writes
    }
}

// ---- slot -> list of output rows (handles duplicate nodes) ----
__global__ void k_outmap(const int* __restrict__ nodes, int n,
                         const int* __restrict__ tmap,
                         int* __restrict__ ocnt, int* __restrict__ olist) {
    int i = blockIdx.x * blockDim.x + threadIdx.x;
    if (i >= n) return;
    int slot = tmap[nodes[i]];                 // always >= 0 after k_targets
    int p = atomicAdd(&ocnt[slot], 1);
    if (p < CAPO) olist[slot * CAPO + p] = i;
}

// ---- single edge pass: deg atomics + capacity-bucket fill ----
__global__ __launch_bounds__(256)
void k_degfill(const int* __restrict__ erow, const int* __restrict__ ecol, int E,
               int* __restrict__ deg, const int* __restrict__ tmap,
               int* __restrict__ cur, int* __restrict__ ebuf) {
    int t = blockIdx.x * blockDim.x + threadIdx.x;
    int base = t * 4;
    if (base >= E) return;
    if (base + 4 <= E) {
        int4 c = *reinterpret_cast<const int4*>(ecol + base);
        atomicAdd(&deg[c.x], 1);
        atomicAdd(&deg[c.y], 1);
        atomicAdd(&deg[c.z], 1);
        atomicAdd(&deg[c.w], 1);
        int s0 = tmap[c.x], s1 = tmap[c.y], s2 = tmap[c.z], s3 = tmap[c.w];
        if ((s0 >= 0) | (s1 >= 0) | (s2 >= 0) | (s3 >= 0)) {
            int4 r = *reinterpret_cast<const int4*>(erow + base);
            if (s0 >= 0) { int p = atomicAdd(&cur[s0], 1); if (p < CAPB) ebuf[s0 * CAPB + p] = r.x; }
            if (s1 >= 0) { int p = atomicAdd(&cur[s1], 1); if (p < CAPB) ebuf[s1 * CAPB + p] = r.y; }
            if (s2 >= 0) { int p = atomicAdd(&cur[s2], 1); if (p < CAPB) ebuf[s2 * CAPB + p] = r.z; }
            if (s3 >= 0) { int p = atomicAdd(&cur[s3], 1); if (p < CAPB) ebuf[s3 * CAPB + p] = r.w; }
        }
    } else {
        for (int i = base; i < E; ++i) {
            int c = ecol[i];
            atomicAdd(&deg[c], 1);
            int s = tmap[c];
            if (s >= 0) { int p = atomicAdd(&cur[s], 1); if (p < CAPB) ebuf[s * CAPB + p] = erow[i]; }
        }
    }
}

// ---- pack W (512x128 f32) into bf16 MFMA B-fragment layout ----
// frag (s,t): lane l holds B[k][c], k = s*32 + (l>>4)*8 + j, c = t*16 + (l&15).
// Linear: wt[((s*8+t)*64 + l)*8 + j]; per-s chunk = 4096 shorts = 8 KB.
__global__ void k_wprep(const float* __restrict__ W, unsigned short* __restrict__ wt) {
    int idx = blockIdx.x * 256 + threadIdx.x;   // 0..65535
    int j  = idx & 7;
    int l  = (idx >> 3) & 63;
    int st = idx >> 9;
    int t  = st & 7, s = st >> 3;
    int k  = s * 32 + (l >> 4) * 8 + j;
    int c  = t * 16 + (l & 15);
    wt[idx] = f2bf(W[(size_t)k * CDIM + c]);
}

// ---- dense h = emb @ W: streaming MFMA GEMM, counted-vmcnt depth-2 pipeline ----
// 512 thr / 8 waves (4 row-groups x 2 col-groups), tile 128x128, BK=32, 16 K-steps.
// 3 buffers: A[128][32] f32 (16 KB, XOR-swizzled via pre-swizzled global source),
// B 4096 bf16 frag-packed (8 KB). stage = 3 global_load_lds per thread.
__global__ __launch_bounds__(512, 4)
void k_gemm_h(const float* __restrict__ emb, const unsigned short* __restrict__ wt,
              unsigned short* __restrict__ h, int N) {
    extern __shared__ char smem[];
    float*          sA = (float*)smem;                        // 3 x 4096 f32
    unsigned short* sB = (unsigned short*)(smem + 3 * 16384); // 3 x 4096 bf16
    int tid  = threadIdx.x;
    int lane = tid & 63;
    int wid  = tid >> 6;
    int wr   = wid >> 1;            // row-group 0..3 (32 rows)
    int wc   = wid & 1;             // col-group 0..1 (64 cols)
    int row0 = blockIdx.x * 128;

    auto stage = [&](int buf, int kc) {
        #pragma unroll
        for (int p = 0; p < 2; ++p) {          // A: 1024 x 16B chunks
            int i = p * 512 + tid;
            int row = i >> 3, chunk = i & 7;
            int swz = chunk ^ (row & 7);       // pre-swizzled source, linear LDS
            int rg = row0 + row; if (rg >= N) rg = N - 1;
            const float* g = emb + (size_t)rg * KDIM + kc * 32 + swz * 4;
            float* l = sA + buf * 4096 + i * 4;
            __builtin_amdgcn_global_load_lds(
                (const __attribute__((address_space(1))) void*)g,
                (__attribute__((address_space(3))) void*)l, 16, 0, 0);
        }
        {                                      // B: 512 x 16B chunks
            const unsigned short* g = wt + (size_t)kc * 4096 + tid * 8;
            unsigned short* l = sB + buf * 4096 + tid * 8;
            __builtin_amdgcn_global_load_lds(
                (const __attribute__((address_space(1))) void*)g,
                (__attribute__((address_space(3))) void*)l, 16, 0, 0);
        }
    };

    f32x4 acc[2][4];
    #pragma unroll
    for (int m = 0; m < 2; ++m)
        #pragma unroll
        for (int t = 0; t < 4; ++t) acc[m][t] = (f32x4){0.f, 0.f, 0.f, 0.f};

    int arow0 = wr * 32 + (lane & 15);
    int kq    = lane >> 4;                     // k-quarter 0..3

    auto compute = [&](int buf) {
        const float*          Ab = sA + buf * 4096;
        const unsigned short* Bb = sB + buf * 4096;
        short8 af[2];
        #pragma unroll
        for (int m = 0; m < 2; ++m) {
            int row = arow0 + m * 16;
            int c0  = kq * 2;
            int s0  = c0 ^ (row & 7);
            int s1  = (c0 + 1) ^ (row & 7);
            float4 v0 = *reinterpret_cast<const float4*>(Ab + row * 32 + s0 * 4);
            float4 v1 = *reinterpret_cast<const float4*>(Ab + row * 32 + s1 * 4);
            af[m][0] = (short)f2bf(v0.x); af[m][1] = (short)f2bf(v0.y);
            af[m][2] = (short)f2bf(v0.z); af[m][3] = (short)f2bf(v0.w);
            af[m][4] = (short)f2bf(v1.x); af[m][5] = (short)f2bf(v1.y);
            af[m][6] = (short)f2bf(v1.z); af[m][7] = (short)f2bf(v1.w);
        }
        #pragma unroll
        for (int tt = 0; tt < 4; ++tt) {
            int t = wc * 4 + tt;
            short8 bf = *reinterpret_cast<const short8*>(Bb + ((size_t)(t * 64 + lane)) * 8);
            acc[0][tt] = __builtin_amdgcn_mfma_f32_16x16x32_bf16(af[0], bf, acc[0][tt], 0, 0, 0);
            acc[1][tt] = __builtin_amdgcn_mfma_f32_16x16x32_bf16(af[1], bf, acc[1][tt], 0, 0, 0);
        }
    };

    stage(0, 0); stage(1, 1); stage(2, 2);     // prologue: 3 tiles in flight (9 loads)

    for (int kc = 0; kc < 14; ++kc) {          // steady state: 2 tiles always in flight
        if (kc > 0) stage((kc + 2) % 3, kc + 2);
        asm volatile("s_waitcnt vmcnt(6)" ::: "memory");   // tile kc ready
        __builtin_amdgcn_s_barrier();
        asm volatile("" ::: "memory");
        compute(kc % 3);
        asm volatile("" ::: "memory");
        __builtin_amdgcn_s_barrier();          // frees buf kc%3
    }
    asm volatile("s_waitcnt vmcnt(3)" ::: "memory");       // kc = 14
    __builtin_amdgcn_s_barrier();
    asm volatile("" ::: "memory");
    compute(2);
    asm volatile("" ::: "memory");
    __builtin_amdgcn_s_barrier();
    asm volatile("s_waitcnt vmcnt(0)" ::: "memory");       // kc = 15
    __builtin_amdgcn_s_barrier();
    asm volatile("" ::: "memory");
    compute(0);

    // D layout (m89-verified): col = lane&15, row = (lane>>4)*4 + reg_idx
    int rbase = row0 + wr * 32 + (lane >> 4) * 4;
    int cbase = wc * 64 + (lane & 15);
    #pragma unroll
    for (int m = 0; m < 2; ++m)
        #pragma unroll
        for (int tt = 0; tt < 4; ++tt)
            #pragma unroll
            for (int j = 0; j < 4; ++j) {
                int r = rbase + m * 16 + j;
                if (r < N) h[(size_t)r * CDIM + cbase + tt * 16] = f2bf(acc[m][tt][j]);
            }
}

// ---- per-target aggregation over h (128-dim bf16): one wave per slot ----
__global__ __launch_bounds__(256)
void k_agg(const unsigned short* __restrict__ h, const int* __restrict__ deg,
           const int* __restrict__ tlist, const int* __restrict__ cur,
           const int* __restrict__ ebuf, const int* __restrict__ ucount,
           const int* __restrict__ ocnt, const int* __restrict__ olist,
           float* __restrict__ out) {
    int u = *ucount;
    int slot = blockIdx.x * 4 + (threadIdx.x >> 6);
    if (slot >= u) return;                 // wave-uniform exit
    int lane = threadIdx.x & 63;
    int e = min(cur[slot], CAPB);
    int myi = 0; float myw = 0.f;
    if (lane < e) {
        myi = ebuf[(size_t)slot * CAPB + lane];          // coalesced
        myw = rsqrtf((float)(deg[myi] + 1));
    }
    float ax = 0.f, ay = 0.f;
    #pragma unroll 4
    for (int j = 0; j < e; ++j) {
        int   src = __shfl(myi, j, 64);
        float w   = __shfl(myw, j, 64);
        unsigned v = *reinterpret_cast<const unsigned*>(h + (size_t)src * CDIM + lane * 2);
        ax += w * bf2f((unsigned short)(v & 0xffffu));
        ay += w * bf2f((unsigned short)(v >> 16));
    }
    int t = tlist[slot];
    float dt = rsqrtf((float)(deg[t] + 1));
    unsigned v = *reinterpret_cast<const unsigned*>(h + (size_t)t * CDIM + lane * 2);
    float rx = dt * (ax + dt * bf2f((unsigned short)(v & 0xffffu)));
    float ry = dt * (ay + dt * bf2f((unsigned short)(v >> 16)));
    int cnt = min(ocnt[slot], CAPO);
    for (int q = 0; q < cnt; ++q) {
        int i = olist[slot * CAPO + q];
        float2 o; o.x = rx; o.y = ry;
        *reinterpret_cast<float2*>(out + (size_t)i * CDIM + lane * 2) = o;  // coalesced
    }
}

extern "C" void kernel_launch(void* const* d_in, const int* in_sizes, int n_in,
                              void* d_out, int out_size, void* d_ws, size_t ws_size,
                              hipStream_t stream) {
    const int*   nodes = (const int*)d_in[0];
    const int*   eidx  = (const int*)d_in[1];
    const float* emb   = (const float*)d_in[2];
    const float* W     = (const float*)d_in[3];
    float*       out   = (float*)d_out;

    int n = in_sizes[0];             // 10000
    int E = in_sizes[1] / 2;         // 1,600,000
    int N = in_sizes[2] / KDIM;      // 100,000
    const int* erow = eidx;          // sources
    const int* ecol = eidx + E;      // targets

    // workspace carve (~30 MB total)
    char* ws = (char*)d_ws;
    size_t o = 0;
    auto carve = [&](size_t bytes) {
        char* p = ws + o;
        o = (o + bytes + 255) & ~(size_t)255;
        return p;
    };
    int* deg    = (int*)carve((size_t)N * 4);
    int* tmap   = (int*)carve((size_t)N * 4);
    int* tlist  = (int*)carve((size_t)n * 4);
    int* cur    = (int*)carve((size_t)n * 4);
    int* ocnt   = (int*)carve((size_t)n * 4);
    int* olist  = (int*)carve((size_t)n * CAPO * 4);
    int* ucount = (int*)carve(4);
    int* ebuf   = (int*)carve((size_t)n * CAPB * 4);
    unsigned short* wt = (unsigned short*)carve((size_t)16 * 8 * 64 * 8 * 2);   // 128 KB
    unsigned short* h  = (unsigned short*)carve((size_t)N * CDIM * 2);          // 25.6 MB
    (void)ws_size; (void)n_in; (void)out_size;

    hipFuncSetAttribute(reinterpret_cast<const void*>(k_gemm_h),
                        hipFuncAttributeMaxDynamicSharedMemorySize, 73728);

    int E4 = (E + 3) / 4;
    k_init   <<<(N + 255) / 256, 256, 0, stream>>>(deg, tmap, cur, ocnt, ucount, N, n);
    k_targets<<<(n + 255) / 256, 256, 0, stream>>>(nodes, n, tmap, tlist, ucount);
    k_outmap <<<(n + 255) / 256, 256, 0, stream>>>(nodes, n, tmap, ocnt, olist);
    k_degfill<<<(E4 + 255) / 256, 256, 0, stream>>>(erow, ecol, E, deg, tmap, cur, ebuf);
    k_wprep  <<<256, 256, 0, stream>>>(W, wt);
    k_gemm_h <<<(N + 127) / 128, 512, 73728, stream>>>(emb, wt, h, N);
    k_agg    <<<(n + 3) / 4, 256, 0, stream>>>(h, deg, tlist, cur, ebuf, ucount,
                                               ocnt, olist, out);
}